// Round 2
// baseline (392.031 us; speedup 1.0000x reference)
//
#include <hip/hip_runtime.h>
#include <hip/hip_bf16.h>

#define SEQ 2048
#define DIM 1024
#define NH  16
#define HD  64
#define SPLIT 4
#define KCOLS (SEQ / SPLIT)   // 512 k-columns per split

typedef __bf16 bf16_t;
typedef __bf16 bf16x4 __attribute__((ext_vector_type(4)));
typedef __bf16 bf16x8 __attribute__((ext_vector_type(8)));
typedef float  f32x4  __attribute__((ext_vector_type(4)));

#define MFMA16(a,b,c) __builtin_amdgcn_mfma_f32_16x16x32_bf16((a),(b),(c),0,0,0)

__device__ __forceinline__ void gload_lds16(const void* g, void* l) {
    __builtin_amdgcn_global_load_lds(
        (const __attribute__((address_space(1))) unsigned int*)g,
        (__attribute__((address_space(3))) unsigned int*)l, 16, 0, 0);
}

// ---------------- cos/sin tables: [2048][32] ----------------
__global__ __launch_bounds__(256) void k_tables(const float* __restrict__ invf,
                                                float* __restrict__ cosT,
                                                float* __restrict__ sinT) {
    int id = blockIdx.x * 256 + threadIdx.x;     // 65536 total
    int t = id >> 5, i = id & 31;
    float f = (float)t * invf[i];
    cosT[id] = cosf(f);
    sinT[id] = sinf(f);
}

// ---------------- f32 -> bf16 convert (x4 per thread) ----------------
__global__ __launch_bounds__(256) void k_cvt(const float* __restrict__ in,
                                             bf16_t* __restrict__ out, int n4) {
    int id = blockIdx.x * 256 + threadIdx.x;
    if (id < n4) {
        float4 v = ((const float4*)in)[id];
        bf16x4 o;
        o[0] = (bf16_t)v.x; o[1] = (bf16_t)v.y; o[2] = (bf16_t)v.z; o[3] = (bf16_t)v.w;
        ((bf16x4*)out)[id] = o;
    }
}

// ---------------- bias concat for fused QKV ----------------
__global__ __launch_bounds__(256) void k_biasqkv(const float* __restrict__ bq,
                                                 const float* __restrict__ bv,
                                                 float* __restrict__ bqkv) {
    int n = blockIdx.x * 256 + threadIdx.x;       // 3072
    bqkv[n] = (n < 1024) ? bq[n] : ((n < 2048) ? 0.0f : bv[n - 2048]);
}

// ---------------- m97-style NT GEMM: C[M][N] = A[M][K] @ W[N][K]^T + bias ----------------
// 256 threads (4 waves 2x2). Tile 128x128, BK=32, double-buffered LDS via global_load_lds.
__global__ __launch_bounds__(256) void gemm128(const bf16_t* __restrict__ A,
                                               const bf16_t* __restrict__ W,
                                               const float* __restrict__ bias,
                                               bf16_t* __restrict__ outBf,
                                               float* __restrict__ outF,
                                               int N, int K) {
    __shared__ __align__(16) bf16_t As[2][128 * 32];
    __shared__ __align__(16) bf16_t Bs[2][128 * 32];
    int tid = threadIdx.x, wid = tid >> 6, lane = tid & 63;
    int lrow = lane >> 4, lcol = lane & 15;
    int wr = wid >> 1, wc = wid & 1;
    int m0 = blockIdx.x * 128, n0 = blockIdx.y * 128;

    // staging: wave wid fills LDS chunks [wid*1024, wid*1024+1024) elems (rows wid*32 .. +32)
    int sr = wid * 32 + (lane >> 2);
    int sc = (lane & 3) * 8;
    const bf16_t* Ag = A + (size_t)(m0 + sr) * K + sc;
    const bf16_t* Wg = W + (size_t)(n0 + sr) * K + sc;

    f32x4 acc[4][4] = {};

#define STAGE(buf, k0) do { \
        gload_lds16(Ag + (k0),          &As[buf][wid * 1024]);       \
        gload_lds16(Ag + 16 * K + (k0), &As[buf][wid * 1024 + 512]); \
        gload_lds16(Wg + (k0),          &Bs[buf][wid * 1024]);       \
        gload_lds16(Wg + 16 * K + (k0), &Bs[buf][wid * 1024 + 512]); \
    } while (0)

    STAGE(0, 0);
    __syncthreads();
    int buf = 0;
    for (int k0 = 0; k0 < K; k0 += 32) {
        if (k0 + 32 < K) STAGE(buf ^ 1, k0 + 32);
        bf16x8 af[4], bfr[4];
#pragma unroll
        for (int mi = 0; mi < 4; mi++)
            af[mi] = *(const bf16x8*)&As[buf][(wr * 64 + mi * 16 + lcol) * 32 + lrow * 8];
#pragma unroll
        for (int ni = 0; ni < 4; ni++)
            bfr[ni] = *(const bf16x8*)&Bs[buf][(wc * 64 + ni * 16 + lcol) * 32 + lrow * 8];
#pragma unroll
        for (int mi = 0; mi < 4; mi++)
#pragma unroll
            for (int ni = 0; ni < 4; ni++)
                acc[mi][ni] = MFMA16(af[mi], bfr[ni], acc[mi][ni]);
        __syncthreads();
        buf ^= 1;
    }
#undef STAGE
#pragma unroll
    for (int ni = 0; ni < 4; ni++) {
        int col = n0 + wc * 64 + ni * 16 + lcol;
        float bb = bias ? bias[col] : 0.0f;
#pragma unroll
        for (int mi = 0; mi < 4; mi++)
#pragma unroll
            for (int j = 0; j < 4; j++) {
                int row = m0 + wr * 64 + mi * 16 + lrow * 4 + j;
                float v = acc[mi][ni][j] + bb;
                if (outBf) outBf[(size_t)row * N + col] = (bf16_t)v;
                else       outF [(size_t)row * N + col] = v;
            }
    }
}

// ---------------- RoPE + scale; zscale folded into K; zs^2 table ----------------
__global__ __launch_bounds__(256) void k_rope(const bf16_t* __restrict__ QKV,
                                              const float* __restrict__ cosT,
                                              const float* __restrict__ sinT,
                                              const float* __restrict__ Zf,
                                              bf16_t* __restrict__ Qr,
                                              bf16_t* __restrict__ Kr,
                                              float* __restrict__ zsq) {
    int id = blockIdx.x * 256 + threadIdx.x;      // 2048*512
    int s = id >> 9, pp = id & 511;
    int h = pp >> 5, i = pp & 31;
    int d0 = h * HD + 2 * i;
    float c  = cosT[s * 32 + i];
    float sn = sinT[s * 32 + i];
    const float scale = 0.3535533905932738f;      // 64^-0.25
    size_t qb = (size_t)s * 3072 + d0;            // Q slice
    size_t kb = qb + 1024;                        // K slice

    float qa = (float)QKV[qb], qbv = (float)QKV[qb + 1];
    Qr[(size_t)s * DIM + d0]     = (bf16_t)((qa * c - qbv * sn) * scale);
    Qr[(size_t)s * DIM + d0 + 1] = (bf16_t)((qa * sn + qbv * c) * scale);

    // zscale from rotated k[...,0] of this (h,s): recompute locally
    float k0a = (float)QKV[(size_t)s * 3072 + 1024 + h * HD];
    float k0b = (float)QKV[(size_t)s * 3072 + 1024 + h * HD + 1];
    float c0  = cosT[s * 32];
    float s0  = sinT[s * 32];
    float ra0 = k0a * c0 - k0b * s0;
    float z = Zf[0];
    float zfac = fminf(fmaxf(log1pf(__expf(z)), 1e-5f), 1e-4f);
    float zs = (ra0 == 0.0f) ? zfac : 1.0f;

    float ka = (float)QKV[kb], kbv = (float)QKV[kb + 1];
    float ra = ka * c - kbv * sn;
    float rb = ka * sn + kbv * c;
    Kr[(size_t)s * DIM + d0]     = (bf16_t)(ra * scale * zs);
    Kr[(size_t)s * DIM + d0 + 1] = (bf16_t)(rb * scale * zs);
    if (i == 0) zsq[h * SEQ + s] = zs * zs;
}

// ---------------- V transpose: Vt[D][S] <- QKV V-slice [S][D] ----------------
__global__ __launch_bounds__(256) void k_transpose(const bf16_t* __restrict__ QKV,
                                                   bf16_t* __restrict__ Vt) {
    __shared__ bf16_t tile[64][66];
    int t = threadIdx.x;
    int c = t & 63, r4 = t >> 6;
    int s0 = blockIdx.x * 64, d0 = blockIdx.y * 64;
#pragma unroll
    for (int i = 0; i < 16; i++) {
        int r = i * 4 + r4;
        tile[r][c] = QKV[(size_t)(s0 + r) * 3072 + 2048 + d0 + c];
    }
    __syncthreads();
#pragma unroll
    for (int i = 0; i < 16; i++) {
        int r = i * 4 + r4;   // d index within tile
        Vt[(size_t)(d0 + r) * SEQ + s0 + c] = tile[c][r];
    }
}

// ---------------- fused attention, split-K flash ----------------
// grid (32, 16, 4): x = q-block(64), y = head, z = k-split. 4 waves, each 16 q-rows.
__global__ __launch_bounds__(256, 4) void k_attn(const bf16_t* __restrict__ Qr,
                                                 const bf16_t* __restrict__ Kr,
                                                 const bf16_t* __restrict__ Vt,
                                                 const float* __restrict__ mask,
                                                 const float* __restrict__ zsq,
                                                 float* __restrict__ qk_out,
                                                 bf16_t* __restrict__ Opart,
                                                 float* __restrict__ Mst,
                                                 float* __restrict__ Lst) {
    __shared__ bf16_t plds[4][16 * 128];
    int tid = threadIdx.x, wid = tid >> 6, lane = tid & 63;
    int lrow = lane >> 4, lcol = lane & 15;
    int h = blockIdx.y, sp = blockIdx.z;
    int q0 = blockIdx.x * 64 + wid * 16;
    int kbase = sp * KCOLS;

    bf16x8 aq[2];
    {
        const bf16_t* qb = Qr + (size_t)(q0 + lcol) * DIM + h * HD + lrow * 8;
        aq[0] = *(const bf16x8*)qb;
        aq[1] = *(const bf16x8*)(qb + 32);
    }

    float m[4] = {-1e30f, -1e30f, -1e30f, -1e30f};
    float l[4] = {0.f, 0.f, 0.f, 0.f};
    f32x4 acc[4] = {};
    char* wl = (char*)&plds[wid][0];
    float* qkbase = qk_out + (size_t)h * SEQ * SEQ;

    for (int kc = kbase; kc < kbase + KCOLS; kc += 128) {
        // ---- QK^T: 8 col-tiles of 16 ----
        f32x4 sfr[8];
#pragma unroll
        for (int ct = 0; ct < 8; ct++) {
            const bf16_t* kb = Kr + (size_t)(kc + ct * 16 + lcol) * DIM + h * HD + lrow * 8;
            bf16x8 b0 = *(const bf16x8*)kb;
            bf16x8 b1 = *(const bf16x8*)(kb + 32);
            f32x4 cacc = {};
            cacc = MFMA16(aq[0], b0, cacc);
            cacc = MFMA16(aq[1], b1, cacc);
            sfr[ct] = cacc;
        }
        // ---- epilogue: qk = s' + mask*zs^2 ; store + row stats ----
        float p[8][4];
        float rmax[4] = {-1e30f, -1e30f, -1e30f, -1e30f};
#pragma unroll
        for (int ct = 0; ct < 8; ct++) {
            int kk = kc + ct * 16 + lcol;
            float zq = zsq[h * SEQ + kk];
#pragma unroll
            for (int j = 0; j < 4; j++) {
                int row = q0 + lrow * 4 + j;
                float mk = mask[(size_t)row * SEQ + kk];
                float v = fmaf(mk, zq, sfr[ct][j]);
                qkbase[(size_t)row * SEQ + kk] = v;
                p[ct][j] = v;
                rmax[j] = fmaxf(rmax[j], v);
            }
        }
#pragma unroll
        for (int j = 0; j < 4; j++) {
            rmax[j] = fmaxf(rmax[j], __shfl_xor(rmax[j], 1));
            rmax[j] = fmaxf(rmax[j], __shfl_xor(rmax[j], 2));
            rmax[j] = fmaxf(rmax[j], __shfl_xor(rmax[j], 4));
            rmax[j] = fmaxf(rmax[j], __shfl_xor(rmax[j], 8));
        }
        float sc[4], lsum[4];
#pragma unroll
        for (int j = 0; j < 4; j++) {
            float mn = fmaxf(m[j], rmax[j]);
            sc[j] = __expf(m[j] - mn);
            m[j] = mn;
            lsum[j] = 0.f;
        }
#pragma unroll
        for (int ct = 0; ct < 8; ct++)
#pragma unroll
            for (int j = 0; j < 4; j++) {
                float e = __expf(p[ct][j] - m[j]);
                p[ct][j] = e;
                lsum[j] += e;
            }
#pragma unroll
        for (int j = 0; j < 4; j++) {
            lsum[j] += __shfl_xor(lsum[j], 1);
            lsum[j] += __shfl_xor(lsum[j], 2);
            lsum[j] += __shfl_xor(lsum[j], 4);
            lsum[j] += __shfl_xor(lsum[j], 8);
            l[j] = l[j] * sc[j] + lsum[j];
        }
#pragma unroll
        for (int ng = 0; ng < 4; ng++)
#pragma unroll
            for (int j = 0; j < 4; j++) acc[ng][j] *= sc[j];

        // ---- P -> LDS (bf16, XOR-swizzled rows) ----
        asm volatile("s_waitcnt lgkmcnt(0)" ::: "memory");  // WAR vs prev-iter reads
#pragma unroll
        for (int ct = 0; ct < 8; ct++)
#pragma unroll
            for (int j = 0; j < 4; j++) {
                int row = lrow * 4 + j;
                int addr = row * 256 + (ct * 16 + lcol) * 2;
                addr ^= (row & 7) << 4;
                *(bf16_t*)(wl + addr) = (bf16_t)p[ct][j];
            }
        asm volatile("s_waitcnt lgkmcnt(0)" ::: "memory");
        __builtin_amdgcn_sched_barrier(0);

        bf16x8 pa[4];
#pragma unroll
        for (int ks = 0; ks < 4; ks++) {
            int addr = lcol * 256 + ks * 64 + lrow * 16;
            addr ^= (lcol & 7) << 4;
            pa[ks] = *(const bf16x8*)(wl + addr);
        }
        // ---- PV ----
#pragma unroll
        for (int ks = 0; ks < 4; ks++) {
#pragma unroll
            for (int ng = 0; ng < 4; ng++) {
                const bf16_t* vb = Vt + (size_t)(h * HD + ng * 16 + lcol) * SEQ + kc + ks * 32 + lrow * 8;
                bf16x8 bv = *(const bf16x8*)vb;
                acc[ng] = MFMA16(pa[ks], bv, acc[ng]);
            }
        }
    }
    // ---- store split partials ----
#pragma unroll
    for (int ng = 0; ng < 4; ng++)
#pragma unroll
        for (int j = 0; j < 4; j++) {
            int row = q0 + lrow * 4 + j;
            size_t idx = ((size_t)(h * SEQ + row) * SPLIT + sp) * HD + ng * 16 + lcol;
            Opart[idx] = (bf16_t)acc[ng][j];
        }
    if (lcol == 0) {
#pragma unroll
        for (int j = 0; j < 4; j++) {
            int row = q0 + lrow * 4 + j;
            size_t idx = (size_t)(h * SEQ + row) * SPLIT + sp;
            Mst[idx] = m[j];
            Lst[idx] = l[j];
        }
    }
}

// ---------------- split-K combine ----------------
__global__ __launch_bounds__(256) void k_combine(const bf16_t* __restrict__ Opart,
                                                 const float* __restrict__ Mst,
                                                 const float* __restrict__ Lst,
                                                 bf16_t* __restrict__ wv) {
    int gid = blockIdx.x * 256 + threadIdx.x;     // NH*SEQ*64
    int rowIdx = gid >> 6, d = gid & 63;
    const float* mp = Mst + (size_t)rowIdx * SPLIT;
    const float* lp = Lst + (size_t)rowIdx * SPLIT;
    float m0 = mp[0], m1 = mp[1], m2 = mp[2], m3 = mp[3];
    float M = fmaxf(fmaxf(m0, m1), fmaxf(m2, m3));
    float w0 = __expf(m0 - M), w1 = __expf(m1 - M), w2 = __expf(m2 - M), w3 = __expf(m3 - M);
    float L = w0 * lp[0] + w1 * lp[1] + w2 * lp[2] + w3 * lp[3];
    const bf16_t* ob = Opart + (size_t)rowIdx * SPLIT * HD + d;
    float O = w0 * (float)ob[0] + w1 * (float)ob[HD] + w2 * (float)ob[2 * HD] + w3 * (float)ob[3 * HD];
    int h = rowIdx >> 11, row = rowIdx & (SEQ - 1);
    wv[(size_t)row * DIM + h * HD + d] = (bf16_t)(O / L);
}

extern "C" void kernel_launch(void* const* d_in, const int* in_sizes, int n_in,
                              void* d_out, int out_size, void* d_ws, size_t ws_size,
                              hipStream_t stream) {
    const float* x    = (const float*)d_in[0];
    const float* mask = (const float*)d_in[1];
    const float* Wq   = (const float*)d_in[2];
    const float* bq   = (const float*)d_in[3];
    const float* Wk   = (const float*)d_in[4];
    const float* Wv   = (const float*)d_in[5];
    const float* bv   = (const float*)d_in[6];
    const float* Wo   = (const float*)d_in[7];
    const float* bo   = (const float*)d_in[8];
    const float* Zf   = (const float*)d_in[9];
    const float* invf = (const float*)d_in[10];

    char* ws = (char*)d_ws;
    size_t off = 0;
    auto alloc = [&](size_t bytes) -> char* {
        char* p = ws + off;
        off += (bytes + 255) & ~(size_t)255;
        return p;
    };
    float*  cosT  = (float*)alloc(65536 * 4);
    float*  sinT  = (float*)alloc(65536 * 4);
    bf16_t* Xb    = (bf16_t*)alloc((size_t)SEQ * DIM * 2);
    bf16_t* Wqkvb = (bf16_t*)alloc((size_t)3 * DIM * DIM * 2);
    bf16_t* Wob   = (bf16_t*)alloc((size_t)DIM * DIM * 2);
    float*  bqkv  = (float*)alloc(3072 * 4);
    bf16_t* QKV   = (bf16_t*)alloc((size_t)SEQ * 3 * DIM * 2);
    bf16_t* Qrp   = (bf16_t*)alloc((size_t)SEQ * DIM * 2);
    bf16_t* Krp   = (bf16_t*)alloc((size_t)SEQ * DIM * 2);
    bf16_t* Vt    = (bf16_t*)alloc((size_t)DIM * SEQ * 2);
    float*  zsq   = (float*)alloc((size_t)NH * SEQ * 4);
    bf16_t* Opart = (bf16_t*)alloc((size_t)NH * SEQ * SPLIT * HD * 2);
    float*  Mst   = (float*)alloc((size_t)NH * SEQ * SPLIT * 4);
    float*  Lst   = (float*)alloc((size_t)NH * SEQ * SPLIT * 4);
    bf16_t* WVb   = (bf16_t*)alloc((size_t)SEQ * DIM * 2);

    float* outp = (float*)d_out;
    float* qkp  = outp + (size_t)SEQ * DIM;   // out is 2048*1024, then qk 16*2048*2048

    k_tables<<<256, 256, 0, stream>>>(invf, cosT, sinT);
    k_cvt<<<(SEQ * DIM / 4 + 255) / 256, 256, 0, stream>>>(x,  Xb, SEQ * DIM / 4);
    k_cvt<<<(DIM * DIM / 4 + 255) / 256, 256, 0, stream>>>(Wq, Wqkvb,                 DIM * DIM / 4);
    k_cvt<<<(DIM * DIM / 4 + 255) / 256, 256, 0, stream>>>(Wk, Wqkvb + DIM * DIM,     DIM * DIM / 4);
    k_cvt<<<(DIM * DIM / 4 + 255) / 256, 256, 0, stream>>>(Wv, Wqkvb + 2 * DIM * DIM, DIM * DIM / 4);
    k_cvt<<<(DIM * DIM / 4 + 255) / 256, 256, 0, stream>>>(Wo, Wob, DIM * DIM / 4);
    k_biasqkv<<<12, 256, 0, stream>>>(bq, bv, bqkv);

    // fused QKV projection: [2048][3072]
    gemm128<<<dim3(SEQ / 128, 3072 / 128), 256, 0, stream>>>(Xb, Wqkvb, bqkv, QKV, nullptr, 3072, DIM);

    k_rope<<<(SEQ * 512) / 256, 256, 0, stream>>>(QKV, cosT, sinT, Zf, Qrp, Krp, zsq);
    k_transpose<<<dim3(SEQ / 64, NH), 256, 0, stream>>>(QKV, Vt);

    k_attn<<<dim3(SEQ / 64, NH, SPLIT), 256, 0, stream>>>(Qrp, Krp, Vt, mask, zsq, qkp,
                                                          Opart, Mst, Lst);
    k_combine<<<(NH * SEQ * HD) / 256, 256, 0, stream>>>(Opart, Mst, Lst, WVb);

    // output projection (f32 out)
    gemm128<<<dim3(SEQ / 128, DIM / 128), 256, 0, stream>>>(WVb, Wob, bo, nullptr, outp, DIM, DIM);
}

// Round 3
// 283.589 us; speedup vs baseline: 1.3824x; 1.3824x over previous
//
#include <hip/hip_runtime.h>
#include <hip/hip_bf16.h>

#define SEQ 2048
#define DIM 1024
#define NH  16
#define HD  64
#define SPLIT 4
#define KCOLS (SEQ / SPLIT)   // 512 k-columns per split
#define KVBLK 64              // k-cols per inner tile

typedef __bf16 bf16_t;
typedef __bf16 bf16x4 __attribute__((ext_vector_type(4)));
typedef __bf16 bf16x8 __attribute__((ext_vector_type(8)));
typedef float  f32x4  __attribute__((ext_vector_type(4)));

#define MFMA16(a,b,c) __builtin_amdgcn_mfma_f32_16x16x32_bf16((a),(b),(c),0,0,0)

__device__ __forceinline__ void gload_lds16(const void* g, void* l) {
    __builtin_amdgcn_global_load_lds(
        (const __attribute__((address_space(1))) unsigned int*)g,
        (__attribute__((address_space(3))) unsigned int*)l, 16, 0, 0);
}

// ---------------- cos/sin tables: [2048][32] ----------------
__global__ __launch_bounds__(256) void k_tables(const float* __restrict__ invf,
                                                float* __restrict__ cosT,
                                                float* __restrict__ sinT) {
    int id = blockIdx.x * 256 + threadIdx.x;     // 65536 total
    int t = id >> 5, i = id & 31;
    float f = (float)t * invf[i];
    cosT[id] = cosf(f);
    sinT[id] = sinf(f);
}

// ---------------- f32 -> bf16 convert (x4 per thread) ----------------
__global__ __launch_bounds__(256) void k_cvt(const float* __restrict__ in,
                                             bf16_t* __restrict__ out, int n4) {
    int id = blockIdx.x * 256 + threadIdx.x;
    if (id < n4) {
        float4 v = ((const float4*)in)[id];
        bf16x4 o;
        o[0] = (bf16_t)v.x; o[1] = (bf16_t)v.y; o[2] = (bf16_t)v.z; o[3] = (bf16_t)v.w;
        ((bf16x4*)out)[id] = o;
    }
}

// ---------------- bias concat for fused QKV ----------------
__global__ __launch_bounds__(256) void k_biasqkv(const float* __restrict__ bq,
                                                 const float* __restrict__ bv,
                                                 float* __restrict__ bqkv) {
    int n = blockIdx.x * 256 + threadIdx.x;       // 3072
    bqkv[n] = (n < 1024) ? bq[n] : ((n < 2048) ? 0.0f : bv[n - 2048]);
}

// ---------------- m97-style NT GEMM: C[M][N] = A[M][K] @ W[N][K]^T + bias ----------------
__global__ __launch_bounds__(256) void gemm128(const bf16_t* __restrict__ A,
                                               const bf16_t* __restrict__ W,
                                               const float* __restrict__ bias,
                                               bf16_t* __restrict__ outBf,
                                               float* __restrict__ outF,
                                               int N, int K) {
    __shared__ __align__(16) bf16_t As[2][128 * 32];
    __shared__ __align__(16) bf16_t Bs[2][128 * 32];
    int tid = threadIdx.x, wid = tid >> 6, lane = tid & 63;
    int lrow = lane >> 4, lcol = lane & 15;
    int wr = wid >> 1, wc = wid & 1;
    int m0 = blockIdx.x * 128, n0 = blockIdx.y * 128;

    int sr = wid * 32 + (lane >> 2);
    int sc = (lane & 3) * 8;
    const bf16_t* Ag = A + (size_t)(m0 + sr) * K + sc;
    const bf16_t* Wg = W + (size_t)(n0 + sr) * K + sc;

    f32x4 acc[4][4] = {};

#define STAGE(buf, k0) do { \
        gload_lds16(Ag + (k0),          &As[buf][wid * 1024]);       \
        gload_lds16(Ag + 16 * K + (k0), &As[buf][wid * 1024 + 512]); \
        gload_lds16(Wg + (k0),          &Bs[buf][wid * 1024]);       \
        gload_lds16(Wg + 16 * K + (k0), &Bs[buf][wid * 1024 + 512]); \
    } while (0)

    STAGE(0, 0);
    __syncthreads();
    int buf = 0;
    for (int k0 = 0; k0 < K; k0 += 32) {
        if (k0 + 32 < K) STAGE(buf ^ 1, k0 + 32);
        bf16x8 af[4], bfr[4];
#pragma unroll
        for (int mi = 0; mi < 4; mi++)
            af[mi] = *(const bf16x8*)&As[buf][(wr * 64 + mi * 16 + lcol) * 32 + lrow * 8];
#pragma unroll
        for (int ni = 0; ni < 4; ni++)
            bfr[ni] = *(const bf16x8*)&Bs[buf][(wc * 64 + ni * 16 + lcol) * 32 + lrow * 8];
#pragma unroll
        for (int mi = 0; mi < 4; mi++)
#pragma unroll
            for (int ni = 0; ni < 4; ni++)
                acc[mi][ni] = MFMA16(af[mi], bfr[ni], acc[mi][ni]);
        __syncthreads();
        buf ^= 1;
    }
#undef STAGE
#pragma unroll
    for (int ni = 0; ni < 4; ni++) {
        int col = n0 + wc * 64 + ni * 16 + lcol;
        float bb = bias ? bias[col] : 0.0f;
#pragma unroll
        for (int mi = 0; mi < 4; mi++)
#pragma unroll
            for (int j = 0; j < 4; j++) {
                int row = m0 + wr * 64 + mi * 16 + lrow * 4 + j;
                float v = acc[mi][ni][j] + bb;
                if (outBf) outBf[(size_t)row * N + col] = (bf16_t)v;
                else       outF [(size_t)row * N + col] = v;
            }
    }
}

// ---------------- RoPE + scale; head-major Qh/Kh; zscale folded into K ----------------
__global__ __launch_bounds__(256) void k_rope(const bf16_t* __restrict__ QKV,
                                              const float* __restrict__ cosT,
                                              const float* __restrict__ sinT,
                                              const float* __restrict__ Zf,
                                              bf16_t* __restrict__ Qh,
                                              bf16_t* __restrict__ Kh,
                                              float* __restrict__ zsq) {
    int id = blockIdx.x * 256 + threadIdx.x;      // 2048*512
    int s = id >> 9, pp = id & 511;
    int h = pp >> 5, i = pp & 31;
    float c  = cosT[s * 32 + i];
    float sn = sinT[s * 32 + i];
    const float scale = 0.3535533905932738f;      // 64^-0.25
    size_t qb = (size_t)s * 3072 + h * HD + 2 * i;  // Q slice
    size_t kb = qb + 1024;                          // K slice
    size_t ob = ((size_t)h * SEQ + s) * HD + 2 * i; // head-major out

    float qa = (float)QKV[qb], qbv = (float)QKV[qb + 1];
    Qh[ob]     = (bf16_t)((qa * c - qbv * sn) * scale);
    Qh[ob + 1] = (bf16_t)((qa * sn + qbv * c) * scale);

    // zscale from rotated k[...,0] of this (h,s)
    float k0a = (float)QKV[(size_t)s * 3072 + 1024 + h * HD];
    float k0b = (float)QKV[(size_t)s * 3072 + 1024 + h * HD + 1];
    float ra0 = k0a * cosT[s * 32] - k0b * sinT[s * 32];
    float z = Zf[0];
    float zfac = fminf(fmaxf(log1pf(__expf(z)), 1e-5f), 1e-4f);
    float zs = (ra0 == 0.0f) ? zfac : 1.0f;

    float ka = (float)QKV[kb], kbv = (float)QKV[kb + 1];
    float ra = ka * c - kbv * sn;
    float rb = ka * sn + kbv * c;
    Kh[ob]     = (bf16_t)(ra * scale * zs);
    Kh[ob + 1] = (bf16_t)(rb * scale * zs);
    if (i == 0) zsq[h * SEQ + s] = zs * zs;
}

// ---------------- V transpose: Vt[D][S] (== head-major [NH][HD][SEQ]) ----------------
__global__ __launch_bounds__(256) void k_transpose(const bf16_t* __restrict__ QKV,
                                                   bf16_t* __restrict__ Vt) {
    __shared__ bf16_t tile[64][66];
    int t = threadIdx.x;
    int c = t & 63, r4 = t >> 6;
    int s0 = blockIdx.x * 64, d0 = blockIdx.y * 64;
#pragma unroll
    for (int i = 0; i < 16; i++) {
        int r = i * 4 + r4;
        tile[r][c] = QKV[(size_t)(s0 + r) * 3072 + 2048 + d0 + c];
    }
    __syncthreads();
#pragma unroll
    for (int i = 0; i < 16; i++) {
        int r = i * 4 + r4;   // d index within tile
        Vt[(size_t)(d0 + r) * SEQ + s0 + c] = tile[c][r];
    }
}

// ---------------- fused attention, split-K flash, KVBLK=64, head-major K ----------------
// grid (32, 16, 4): x = q-block(64), y = head, z = k-split. 4 waves, each 16 q-rows.
__global__ void k_attn(const bf16_t* __restrict__ Qh,
                       const bf16_t* __restrict__ Kh,
                       const bf16_t* __restrict__ Vt,
                       const float* __restrict__ mask,
                       const float* __restrict__ zsq,
                       float* __restrict__ qk_out,
                       bf16_t* __restrict__ Opart,
                       float* __restrict__ Mst,
                       float* __restrict__ Lst) {
    __shared__ bf16_t plds[4][16 * KVBLK];
    int tid = threadIdx.x, wid = tid >> 6, lane = tid & 63;
    int lrow = lane >> 4, lcol = lane & 15;
    int h = blockIdx.y, sp = blockIdx.z;
    int q0 = blockIdx.x * 64 + wid * 16;
    int kbase = sp * KCOLS;

    bf16x8 aq[2];
    {
        const bf16_t* qb = Qh + ((size_t)h * SEQ + q0 + lcol) * HD + lrow * 8;
        aq[0] = *(const bf16x8*)qb;
        aq[1] = *(const bf16x8*)(qb + 32);
    }

    float m[4] = {-1e30f, -1e30f, -1e30f, -1e30f};
    float l[4] = {0.f, 0.f, 0.f, 0.f};
    f32x4 acc[4] = {};
    char* wl = (char*)&plds[wid][0];
    float* qkbase = qk_out + (size_t)h * SEQ * SEQ;
    const bf16_t* khead = Kh + (size_t)h * SEQ * HD;
    const float*  zrow  = zsq + h * SEQ;

    for (int kc = kbase; kc < kbase + KCOLS; kc += KVBLK) {
        // ---- QK^T: 4 col-tiles of 16 ----
        float p[4][4];
#pragma unroll
        for (int ct = 0; ct < 4; ct++) {
            const bf16_t* kb = khead + (size_t)(kc + ct * 16 + lcol) * HD + lrow * 8;
            bf16x8 b0 = *(const bf16x8*)kb;
            bf16x8 b1 = *(const bf16x8*)(kb + 32);
            f32x4 cacc = {};
            cacc = MFMA16(aq[0], b0, cacc);
            cacc = MFMA16(aq[1], b1, cacc);
#pragma unroll
            for (int j = 0; j < 4; j++) p[ct][j] = cacc[j];
        }
        // ---- epilogue: qk = s' + mask*zs^2 ; nontemporal store + row stats ----
        float rmax[4] = {-1e30f, -1e30f, -1e30f, -1e30f};
#pragma unroll
        for (int ct = 0; ct < 4; ct++) {
            int kk = kc + ct * 16 + lcol;
            float zq = zrow[kk];
#pragma unroll
            for (int j = 0; j < 4; j++) {
                int row = q0 + lrow * 4 + j;
                float mk = mask[(size_t)row * SEQ + kk];
                float v = fmaf(mk, zq, p[ct][j]);
                __builtin_nontemporal_store(v, &qkbase[(size_t)row * SEQ + kk]);
                p[ct][j] = v;
                rmax[j] = fmaxf(rmax[j], v);
            }
        }
#pragma unroll
        for (int j = 0; j < 4; j++) {
            rmax[j] = fmaxf(rmax[j], __shfl_xor(rmax[j], 1));
            rmax[j] = fmaxf(rmax[j], __shfl_xor(rmax[j], 2));
            rmax[j] = fmaxf(rmax[j], __shfl_xor(rmax[j], 4));
            rmax[j] = fmaxf(rmax[j], __shfl_xor(rmax[j], 8));
        }
        float sc[4], lsum[4];
#pragma unroll
        for (int j = 0; j < 4; j++) {
            float mn = fmaxf(m[j], rmax[j]);
            sc[j] = __expf(m[j] - mn);
            m[j] = mn;
            lsum[j] = 0.f;
        }
#pragma unroll
        for (int ct = 0; ct < 4; ct++)
#pragma unroll
            for (int j = 0; j < 4; j++) {
                float e = __expf(p[ct][j] - m[j]);
                p[ct][j] = e;
                lsum[j] += e;
            }
#pragma unroll
        for (int j = 0; j < 4; j++) {
            lsum[j] += __shfl_xor(lsum[j], 1);
            lsum[j] += __shfl_xor(lsum[j], 2);
            lsum[j] += __shfl_xor(lsum[j], 4);
            lsum[j] += __shfl_xor(lsum[j], 8);
            l[j] = l[j] * sc[j] + lsum[j];
        }
#pragma unroll
        for (int ng = 0; ng < 4; ng++)
#pragma unroll
            for (int j = 0; j < 4; j++) acc[ng][j] *= sc[j];

        // ---- P -> LDS (bf16, XOR-swizzled rows, 16x64) ----
        asm volatile("s_waitcnt lgkmcnt(0)" ::: "memory");  // WAR vs prev-iter reads
#pragma unroll
        for (int ct = 0; ct < 4; ct++)
#pragma unroll
            for (int j = 0; j < 4; j++) {
                int row = lrow * 4 + j;
                int addr = row * 128 + (ct * 16 + lcol) * 2;
                addr ^= (row & 7) << 4;
                *(bf16_t*)(wl + addr) = (bf16_t)p[ct][j];
            }
        asm volatile("s_waitcnt lgkmcnt(0)" ::: "memory");
        __builtin_amdgcn_sched_barrier(0);

        bf16x8 pa[2];
#pragma unroll
        for (int ks = 0; ks < 2; ks++) {
            int addr = lcol * 128 + ks * 64 + lrow * 16;
            addr ^= (lcol & 7) << 4;
            pa[ks] = *(const bf16x8*)(wl + addr);
        }
        // ---- PV ----
#pragma unroll
        for (int ks = 0; ks < 2; ks++) {
#pragma unroll
            for (int ng = 0; ng < 4; ng++) {
                const bf16_t* vb = Vt + (size_t)(h * HD + ng * 16 + lcol) * SEQ + kc + ks * 32 + lrow * 8;
                bf16x8 bv = *(const bf16x8*)vb;
                acc[ng] = MFMA16(pa[ks], bv, acc[ng]);
            }
        }
    }
    // ---- store split partials ----
#pragma unroll
    for (int ng = 0; ng < 4; ng++)
#pragma unroll
        for (int j = 0; j < 4; j++) {
            int row = q0 + lrow * 4 + j;
            size_t idx = ((size_t)(h * SEQ + row) * SPLIT + sp) * HD + ng * 16 + lcol;
            Opart[idx] = (bf16_t)acc[ng][j];
        }
    if (lcol == 0) {
#pragma unroll
        for (int j = 0; j < 4; j++) {
            int row = q0 + lrow * 4 + j;
            size_t idx = (size_t)(h * SEQ + row) * SPLIT + sp;
            Mst[idx] = m[j];
            Lst[idx] = l[j];
        }
    }
}

// ---------------- split-K combine ----------------
__global__ __launch_bounds__(256) void k_combine(const bf16_t* __restrict__ Opart,
                                                 const float* __restrict__ Mst,
                                                 const float* __restrict__ Lst,
                                                 bf16_t* __restrict__ wv) {
    int gid = blockIdx.x * 256 + threadIdx.x;     // NH*SEQ*64
    int rowIdx = gid >> 6, d = gid & 63;
    const float* mp = Mst + (size_t)rowIdx * SPLIT;
    const float* lp = Lst + (size_t)rowIdx * SPLIT;
    float m0 = mp[0], m1 = mp[1], m2 = mp[2], m3 = mp[3];
    float M = fmaxf(fmaxf(m0, m1), fmaxf(m2, m3));
    float w0 = __expf(m0 - M), w1 = __expf(m1 - M), w2 = __expf(m2 - M), w3 = __expf(m3 - M);
    float L = w0 * lp[0] + w1 * lp[1] + w2 * lp[2] + w3 * lp[3];
    const bf16_t* ob = Opart + (size_t)rowIdx * SPLIT * HD + d;
    float O = w0 * (float)ob[0] + w1 * (float)ob[HD] + w2 * (float)ob[2 * HD] + w3 * (float)ob[3 * HD];
    int h = rowIdx >> 11, row = rowIdx & (SEQ - 1);
    wv[(size_t)row * DIM + h * HD + d] = (bf16_t)(O / L);
}

extern "C" void kernel_launch(void* const* d_in, const int* in_sizes, int n_in,
                              void* d_out, int out_size, void* d_ws, size_t ws_size,
                              hipStream_t stream) {
    const float* x    = (const float*)d_in[0];
    const float* mask = (const float*)d_in[1];
    const float* Wq   = (const float*)d_in[2];
    const float* bq   = (const float*)d_in[3];
    const float* Wk   = (const float*)d_in[4];
    const float* Wv   = (const float*)d_in[5];
    const float* bv   = (const float*)d_in[6];
    const float* Wo   = (const float*)d_in[7];
    const float* bo   = (const float*)d_in[8];
    const float* Zf   = (const float*)d_in[9];
    const float* invf = (const float*)d_in[10];

    char* ws = (char*)d_ws;
    size_t off = 0;
    auto alloc = [&](size_t bytes) -> char* {
        char* p = ws + off;
        off += (bytes + 255) & ~(size_t)255;
        return p;
    };
    float*  cosT  = (float*)alloc(65536 * 4);
    float*  sinT  = (float*)alloc(65536 * 4);
    bf16_t* Xb    = (bf16_t*)alloc((size_t)SEQ * DIM * 2);
    bf16_t* Wqkvb = (bf16_t*)alloc((size_t)3 * DIM * DIM * 2);
    bf16_t* Wob   = (bf16_t*)alloc((size_t)DIM * DIM * 2);
    float*  bqkv  = (float*)alloc(3072 * 4);
    bf16_t* QKV   = (bf16_t*)alloc((size_t)SEQ * 3 * DIM * 2);
    bf16_t* Qhp   = (bf16_t*)alloc((size_t)SEQ * DIM * 2);
    bf16_t* Khp   = (bf16_t*)alloc((size_t)SEQ * DIM * 2);
    bf16_t* Vt    = (bf16_t*)alloc((size_t)DIM * SEQ * 2);
    float*  zsq   = (float*)alloc((size_t)NH * SEQ * 4);
    bf16_t* Opart = (bf16_t*)alloc((size_t)NH * SEQ * SPLIT * HD * 2);
    float*  Mst   = (float*)alloc((size_t)NH * SEQ * SPLIT * 4);
    float*  Lst   = (float*)alloc((size_t)NH * SEQ * SPLIT * 4);
    bf16_t* WVb   = (bf16_t*)alloc((size_t)SEQ * DIM * 2);

    float* outp = (float*)d_out;
    float* qkp  = outp + (size_t)SEQ * DIM;   // out is 2048*1024, then qk 16*2048*2048

    k_tables<<<256, 256, 0, stream>>>(invf, cosT, sinT);
    k_cvt<<<(SEQ * DIM / 4 + 255) / 256, 256, 0, stream>>>(x,  Xb, SEQ * DIM / 4);
    k_cvt<<<(DIM * DIM / 4 + 255) / 256, 256, 0, stream>>>(Wq, Wqkvb,                 DIM * DIM / 4);
    k_cvt<<<(DIM * DIM / 4 + 255) / 256, 256, 0, stream>>>(Wk, Wqkvb + DIM * DIM,     DIM * DIM / 4);
    k_cvt<<<(DIM * DIM / 4 + 255) / 256, 256, 0, stream>>>(Wv, Wqkvb + 2 * DIM * DIM, DIM * DIM / 4);
    k_cvt<<<(DIM * DIM / 4 + 255) / 256, 256, 0, stream>>>(Wo, Wob, DIM * DIM / 4);
    k_biasqkv<<<12, 256, 0, stream>>>(bq, bv, bqkv);

    // fused QKV projection: [2048][3072]
    gemm128<<<dim3(SEQ / 128, 3072 / 128), 256, 0, stream>>>(Xb, Wqkvb, bqkv, QKV, nullptr, 3072, DIM);

    k_rope<<<(SEQ * 512) / 256, 256, 0, stream>>>(QKV, cosT, sinT, Zf, Qhp, Khp, zsq);
    k_transpose<<<dim3(SEQ / 64, NH), 256, 0, stream>>>(QKV, Vt);

    k_attn<<<dim3(SEQ / 64, NH, SPLIT), 256, 0, stream>>>(Qhp, Khp, Vt, mask, zsq, qkp,
                                                          Opart, Mst, Lst);
    k_combine<<<(NH * SEQ * HD) / 256, 256, 0, stream>>>(Opart, Mst, Lst, WVb);

    // output projection (f32 out)
    gemm128<<<dim3(SEQ / 128, DIM / 128), 256, 0, stream>>>(WVb, Wob, bo, nullptr, outp, DIM, DIM);
}